// Round 1
// 71.990 us; speedup vs baseline: 1.0233x; 1.0233x over previous
//
#include <hip/hip_runtime.h>

// out[b,u] = prod_f(inputs[b,f] * weight[f,u]) + bias[u]
//          = (prod_f inputs[b,f]) * (prod_f weight[f,u]) + bias[u]
// B=32768, F=32, U=256.
// R3: non-temporal streaming for the 32MB output and 4MB input (neither is
// reused) so L2 stays dedicated to the 32KB weight matrix that every block
// re-reads. Input load hoisted ahead of the 32 weight loads to overlap its
// cold-HBM latency with the L2-hot Pw chain.
// Mandatory traffic: 4MB in + 32MB out -> ~5.8us at 6.3 TB/s achievable.

#define F 32
#define U 256
#define ROWS_PER_BLOCK 32

typedef float f32x4 __attribute__((ext_vector_type(4)));

__global__ __launch_bounds__(256)
void fused_kernel(const float* __restrict__ inp,
                  const float* __restrict__ weight,
                  const float* __restrict__ bias,
                  float* __restrict__ out) {
  __shared__ float partial[256];            // per-float4 products of input tile
  __shared__ float pin_s[ROWS_PER_BLOCK];   // per-row input products
  __shared__ float pw_s[U];                 // per-column weight products

  const int tid = threadIdx.x;
  const int base = blockIdx.x * ROWS_PER_BLOCK;

  // ---- input tile: issue FIRST (cold HBM, longest latency; overlaps Pw) ----
  // 32 rows x 32 floats = 4KB, one float4 per thread. Read exactly once ->
  // non-temporal, don't allocate in L2.
  const f32x4 x = __builtin_nontemporal_load(
      (const f32x4*)(inp + (size_t)base * F + tid * 4));

  // ---- Pw[u]: each thread owns one column; loads coalesced across lanes ----
  // weight is 32KB and re-read by all 1024 blocks: keep it L2-resident.
  {
    float p = 1.0f;
#pragma unroll
    for (int f = 0; f < F; ++f) p *= weight[f * U + tid];
    pw_s[tid] = p;
  }

  partial[tid] = x.x * x.y * x.z * x.w;
  __syncthreads();

  // ---- row products: 8 partials per row ----
  if (tid < ROWS_PER_BLOCK) {
    float p = 1.0f;
#pragma unroll
    for (int k = 0; k < 8; ++k) p *= partial[tid * 8 + k];
    pin_s[tid] = p;
  }
  __syncthreads();

  // ---- epilogue: wave w stores rows {w, w+4, ..., w+28}, 1KB/wave/step ----
  // Output is write-once streaming: non-temporal stores bypass L2 allocate
  // so the 32MB stream doesn't evict the weight working set.
  const int lane = tid & 63;
  const int wave = tid >> 6;
  const f32x4 w4 = *(const f32x4*)(&pw_s[lane * 4]);
  const f32x4 b4 = *(const f32x4*)(bias + lane * 4);
#pragma unroll
  for (int g = 0; g < 8; ++g) {
    const int r = g * 4 + wave;
    const float p = pin_s[r];  // LDS broadcast
    f32x4 o;
    o.x = p * w4.x + b4.x;
    o.y = p * w4.y + b4.y;
    o.z = p * w4.z + b4.z;
    o.w = p * w4.w + b4.w;
    __builtin_nontemporal_store(o, (f32x4*)(out + (size_t)(base + r) * U + lane * 4));
  }
}

extern "C" void kernel_launch(void* const* d_in, const int* in_sizes, int n_in,
                              void* d_out, int out_size, void* d_ws, size_t ws_size,
                              hipStream_t stream) {
  const float* inp    = (const float*)d_in[0];  // [B, F]
  const float* weight = (const float*)d_in[1];  // [F, U]
  // d_in[2] = weight_selector: dead code in the reference, unused
  const float* bias   = (const float*)d_in[3];  // [U]
  float* out = (float*)d_out;                   // [B, U]

  const int B = in_sizes[0] / F;
  fused_kernel<<<B / ROWS_PER_BLOCK, 256, 0, stream>>>(inp, weight, bias, out);
}